// Round 1
// baseline (96.606 us; speedup 1.0000x reference)
//
#include <hip/hip_runtime.h>

// Problem constants (from reference): B=128, T=32, D=512, R=256, R2=128.
// Analytical collapse: r_new = zeros every scan step and r2 stays zeros, so
// r_p = 0 -> r_bar = 0 -> temp_loss = 0, x_hat = x_bar = b_sd. The only
// nontrivial compute is:
//   sl_rhat = sum_t mean_b sum_d (b_sd[d] - X[b,t,d])^2   (t = 0..T-1)
//   sl_rbar = sl_rhat - (t==0 term)
// Outputs (flat, 49156 f32): [sl_rhat, sl_rbar, 0, 0, r0=zeros(128*256), r2=zeros(128*128)]

#define BB 128
#define TT 32
#define DD 512

// Kernel 1: zero the whole output buffer (r0/r2/scalars) and the ws accumulators.
__global__ void k_zero(float* __restrict__ out, int n, float* __restrict__ ws) {
    int i = blockIdx.x * blockDim.x + threadIdx.x;
    int stride = gridDim.x * blockDim.x;
    for (; i < n; i += stride) out[i] = 0.0f;
    if (blockIdx.x == 0 && threadIdx.x < 2) ws[threadIdx.x] = 0.0f;
}

// Kernel 2: reduce sum of (X - b_sd)^2 over all (b,t,d), and separately the t==0 slice.
// X layout (B,T,D); float4 over D (512 % 4 == 0, all 4 elems share b,t).
__global__ void __launch_bounds__(256) k_reduce(const float* __restrict__ X,
                                               const float* __restrict__ b_sd,
                                               float* __restrict__ ws) {
    const int n4 = BB * TT * DD / 4;       // 524288 float4s
    const int d4n = DD / 4;                // 128 float4s per row
    const float4* __restrict__ X4 = (const float4*)X;
    const float4* __restrict__ B4 = (const float4*)b_sd;

    float acc_all = 0.0f, acc_t0 = 0.0f;
    for (int i = blockIdx.x * blockDim.x + threadIdx.x; i < n4;
         i += gridDim.x * blockDim.x) {
        int row = i / d4n;                 // = b*T + t
        int t   = row & (TT - 1);          // T = 32 (pow2)
        int d4  = i - row * d4n;
        float4 x = X4[i];
        float4 c = B4[d4];
        float ex = x.x - c.x, ey = x.y - c.y, ez = x.z - c.z, ew = x.w - c.w;
        float s = ex * ex + ey * ey + ez * ez + ew * ew;
        acc_all += s;
        if (t == 0) acc_t0 += s;
    }

    // wave-64 butterfly reduce
    for (int off = 32; off > 0; off >>= 1) {
        acc_all += __shfl_down(acc_all, off, 64);
        acc_t0  += __shfl_down(acc_t0, off, 64);
    }
    __shared__ float s_all[4], s_t0[4];
    int lane = threadIdx.x & 63, wid = threadIdx.x >> 6;
    if (lane == 0) { s_all[wid] = acc_all; s_t0[wid] = acc_t0; }
    __syncthreads();
    if (threadIdx.x == 0) {
        float a  = s_all[0] + s_all[1] + s_all[2] + s_all[3];
        float t0 = s_t0[0] + s_t0[1] + s_t0[2] + s_t0[3];
        atomicAdd(&ws[0], a);   // device-scope by default (G12)
        atomicAdd(&ws[1], t0);
    }
}

// Kernel 3: finalize the four scalars.
__global__ void k_final(const float* __restrict__ ws, float* __restrict__ out) {
    if (threadIdx.x == 0) {
        const float invB = 1.0f / (float)BB;
        float all = ws[0], t0 = ws[1];
        out[0] = all * invB;          // sl_rhat
        out[1] = (all - t0) * invB;   // sl_rbar
        out[2] = 0.0f;                // TEMP_WEIGHT * temp_loss
        out[3] = 0.0f;                // r2_losses
    }
}

extern "C" void kernel_launch(void* const* d_in, const int* in_sizes, int n_in,
                              void* d_out, int out_size, void* d_ws, size_t ws_size,
                              hipStream_t stream) {
    const float* X    = (const float*)d_in[0];   // (B,T,D)
    const float* b_sd = (const float*)d_in[3];   // (D,)
    float* out = (float*)d_out;                  // 49156 floats
    float* ws  = (float*)d_ws;

    k_zero<<<96, 256, 0, stream>>>(out, out_size, ws);
    k_reduce<<<512, 256, 0, stream>>>(X, b_sd, ws);
    k_final<<<1, 64, 0, stream>>>(ws, out);
}

// Round 2
// 82.435 us; speedup vs baseline: 1.1719x; 1.1719x over previous
//
#include <hip/hip_runtime.h>

// Problem constants (from reference): B=128, T=32, D=512, R=256, R2=128.
// Analytical collapse: r_new = zeros every scan step and r2 stays zeros, so
// r_p = 0 -> r_bar = 0 -> temp_loss = 0, x_hat = x_bar = b_sd. The only
// nontrivial compute is:
//   sl_rhat = sum_t mean_b sum_d (b_sd[d] - X[b,t,d])^2   (t = 0..T-1)
//   sl_rbar = sl_rhat - (t==0 term)
// Outputs (flat, 49156 f32): [sl_rhat, sl_rbar, 0, 0, r0=zeros(128*256), r2=zeros(128*128)]
//
// R2 structure: 2 kernels, no atomics, no ws init needed.
//  k_main  (512 blocks): zero out[4..], reduce partials, write per-block ws slots.
//  k_final (1 block):    sum 2x512 partials, write out[0..3].

#define BB 128
#define TT 32
#define DD 512
#define NBLK 512

__global__ void __launch_bounds__(256) k_main(const float* __restrict__ X,
                                              const float* __restrict__ b_sd,
                                              float* __restrict__ out,
                                              float* __restrict__ ws) {
    const int tid = blockIdx.x * blockDim.x + threadIdx.x;

    // --- zero out[4 .. 49155] (12288 float4s starting at out+4, 16B-aligned) ---
    {
        float4* __restrict__ o4 = (float4*)(out + 4);
        const int nz4 = (BB * 256 + BB * 128) / 4;  // r0 + r2 = 49152 floats = 12288 f4
        if (tid < nz4) o4[tid] = make_float4(0.f, 0.f, 0.f, 0.f);
    }

    // --- reduce sum of (X - b_sd)^2, all-t and t==0 slice ---
    const int n4  = BB * TT * DD / 4;      // 524288 float4s
    const int d4n = DD / 4;                // 128 float4s per (b,t) row
    const float4* __restrict__ X4 = (const float4*)X;
    const float4* __restrict__ B4 = (const float4*)b_sd;

    float acc_all = 0.0f, acc_t0 = 0.0f;
    for (int i = tid; i < n4; i += NBLK * 256) {
        int row = i / d4n;                 // = b*T + t
        int t   = row & (TT - 1);          // T = 32 (pow2)
        int d4  = i - row * d4n;
        float4 x = X4[i];
        float4 c = B4[d4];
        float ex = x.x - c.x, ey = x.y - c.y, ez = x.z - c.z, ew = x.w - c.w;
        float s = ex * ex + ey * ey + ez * ez + ew * ew;
        acc_all += s;
        if (t == 0) acc_t0 += s;
    }

    // wave-64 butterfly reduce
    for (int off = 32; off > 0; off >>= 1) {
        acc_all += __shfl_down(acc_all, off, 64);
        acc_t0  += __shfl_down(acc_t0, off, 64);
    }
    __shared__ float s_all[4], s_t0[4];
    const int lane = threadIdx.x & 63, wid = threadIdx.x >> 6;
    if (lane == 0) { s_all[wid] = acc_all; s_t0[wid] = acc_t0; }
    __syncthreads();
    if (threadIdx.x == 0) {
        // unconditional per-block slot writes: poisoned ws needs no init
        ws[blockIdx.x]        = s_all[0] + s_all[1] + s_all[2] + s_all[3];
        ws[1024 + blockIdx.x] = s_t0[0]  + s_t0[1]  + s_t0[2]  + s_t0[3];
    }
}

__global__ void __launch_bounds__(256) k_final(const float* __restrict__ ws,
                                               float* __restrict__ out) {
    const int t = threadIdx.x;
    float a  = ws[t]        + ws[t + 256];         // 512 partials, 2/thread
    float t0 = ws[1024 + t] + ws[1024 + t + 256];
    for (int off = 32; off > 0; off >>= 1) {
        a  += __shfl_down(a, off, 64);
        t0 += __shfl_down(t0, off, 64);
    }
    __shared__ float s_a[4], s_t[4];
    const int lane = t & 63, wid = t >> 6;
    if (lane == 0) { s_a[wid] = a; s_t[wid] = t0; }
    __syncthreads();
    if (t == 0) {
        float all = s_a[0] + s_a[1] + s_a[2] + s_a[3];
        float z0  = s_t[0] + s_t[1] + s_t[2] + s_t[3];
        const float invB = 1.0f / (float)BB;
        out[0] = all * invB;          // sl_rhat
        out[1] = (all - z0) * invB;   // sl_rbar
        out[2] = 0.0f;                // TEMP_WEIGHT * temp_loss
        out[3] = 0.0f;                // r2_losses
    }
}

extern "C" void kernel_launch(void* const* d_in, const int* in_sizes, int n_in,
                              void* d_out, int out_size, void* d_ws, size_t ws_size,
                              hipStream_t stream) {
    const float* X    = (const float*)d_in[0];   // (B,T,D)
    const float* b_sd = (const float*)d_in[3];   // (D,)
    float* out = (float*)d_out;                  // 49156 floats
    float* ws  = (float*)d_ws;

    k_main<<<NBLK, 256, 0, stream>>>(X, b_sd, out, ws);
    k_final<<<1, 256, 0, stream>>>(ws, out);
}